// Round 1
// 87.475 us; speedup vs baseline: 1.1040x; 1.1040x over previous
//
#include <hip/hip_runtime.h>
#include <cstdint>

// Problem constants (fixed by setup_inputs): (8, 4096, 6) fp32 both inputs.
#define NB 8
#define NP 4096
#define THREADS 256
#define Q 8                    // query points per thread (registers)
#define CHUNK (THREADS * Q)    // 2048 queries per block
#define NCHUNK (NP / CHUNK)    // 2
#define G 4                    // targets per group (max-tree width)

// Per-pair inner math: s = q·t - 0.5|t|^2 (3 FMA, .w of LDS float4 holds the
// -0.5|t|^2 bias). Argmax is tracked at GROUP granularity: per 4 targets we
// take a v_max tree (3 ops) and one cmp+2*cndmask for {group-max, group-base}
// -> 4.5 VALU/pair instead of 6. The exact winning index inside the group is
// recovered per query in the epilogue by recomputing the identical fmaf
// chains from LDS (bit-identical values; strict > across groups + first-match
// within group == global first-index argmin).
// Block epilogue reconstructs d = |q|^2 - 2s and writes a packed partial
// (float bits of d chopped to 20 bits | 12-bit target idx) to a private
// slot -- no atomics. finish min-reduces partials.

template <int SEGV>
__global__ __launch_bounds__(THREADS) void chamfer_argmin(
    const float* __restrict__ xyz1, const float* __restrict__ xyz2,
    unsigned int* __restrict__ part, float* __restrict__ out)
{
    const int TSEG = NP / SEGV;
    __shared__ float4 tgt[NP / 16];          // max TSEG we instantiate (SEG>=16)

    unsigned int x = blockIdx.x;             // (((dir*8+b)*NCHUNK+chunk)*SEG+seg)
    if (x == 0 && threadIdx.x == 0) out[0] = 0.0f;  // replaces hipMemsetAsync
    int seg   = x & (SEGV - 1);
    int chunk = (x / SEGV) & (NCHUNK - 1);
    int b     = (x / (SEGV * NCHUNK)) & 7;
    int dir   = x / (SEGV * NCHUNK * 8);

    const float* qset = dir ? xyz2 : xyz1;
    const float* tset = dir ? xyz1 : xyz2;

    // Stage this segment's targets into LDS with the -0.5|t|^2 bias in .w.
    int tbase = seg * TSEG;
    for (int t0 = threadIdx.x; t0 < TSEG; t0 += THREADS) {
        const float* src = tset + ((size_t)b * NP + tbase + t0) * 6;
        float tx = src[0], ty = src[1], tz = src[2];
        tgt[t0] = make_float4(tx, ty, tz, -0.5f * (tx * tx + ty * ty + tz * tz));
    }
    __syncthreads();

    // Load Q query points into registers (stride THREADS between qi).
    float qx[Q], qy[Q], qz[Q], qq[Q], bs[Q];
    unsigned int bi[Q];                      // group-base index (segment-local)
    int qbase = chunk * CHUNK + threadIdx.x;
    #pragma unroll
    for (int i = 0; i < Q; ++i) {
        const float* src = qset + ((size_t)b * NP + qbase + i * THREADS) * 6;
        qx[i] = src[0]; qy[i] = src[1]; qz[i] = src[2];
        qq[i] = qx[i] * qx[i] + qy[i] * qy[i] + qz[i] * qz[i];
        bs[i] = -3.4e38f;
        bi[i] = 0u;
    }

    // Inner scan: LDS reads wave-uniform (broadcast), 4.5 VALU/pair.
    #pragma unroll 2
    for (int k = 0; k < TSEG; k += G) {
        float4 t0 = tgt[k + 0];
        float4 t1 = tgt[k + 1];
        float4 t2 = tgt[k + 2];
        float4 t3 = tgt[k + 3];
        #pragma unroll
        for (int i = 0; i < Q; ++i) {
            float s0 = fmaf(t0.x, qx[i], fmaf(t0.y, qy[i], fmaf(t0.z, qz[i], t0.w)));
            float s1 = fmaf(t1.x, qx[i], fmaf(t1.y, qy[i], fmaf(t1.z, qz[i], t1.w)));
            float s2 = fmaf(t2.x, qx[i], fmaf(t2.y, qy[i], fmaf(t2.z, qz[i], t2.w)));
            float s3 = fmaf(t3.x, qx[i], fmaf(t3.y, qy[i], fmaf(t3.z, qz[i], t3.w)));
            float m  = fmaxf(fmaxf(s0, s1), fmaxf(s2, s3));
            if (m > bs[i]) { bs[i] = m; bi[i] = (unsigned int)k; }  // strict >
        }
    }

    // Disambiguate within the winning group (exact recompute, first match),
    // then write private partial slots: coalesced plain stores.
    unsigned int* slot =
        part + (((size_t)(dir * NB + b) * SEGV + seg) * NP) + qbase;
    #pragma unroll
    for (int i = 0; i < Q; ++i) {
        int k = (int)bi[i];
        float4 t0 = tgt[k + 0];
        float4 t1 = tgt[k + 1];
        float4 t2 = tgt[k + 2];
        float4 t3 = tgt[k + 3];
        float s0 = fmaf(t0.x, qx[i], fmaf(t0.y, qy[i], fmaf(t0.z, qz[i], t0.w)));
        float s1 = fmaf(t1.x, qx[i], fmaf(t1.y, qy[i], fmaf(t1.z, qz[i], t1.w)));
        float s2 = fmaf(t2.x, qx[i], fmaf(t2.y, qy[i], fmaf(t2.z, qz[i], t2.w)));
        unsigned int j  = (unsigned int)(tbase + k);
        unsigned int jj = j + 3;
        jj = (s2 == bs[i]) ? j + 2 : jj;     // descending chain -> first index
        jj = (s1 == bs[i]) ? j + 1 : jj;
        jj = (s0 == bs[i]) ? j     : jj;
        float d = fmaxf(fmaf(-2.0f, bs[i], qq[i]), 0.0f);
        slot[i * THREADS] = (__float_as_uint(d) & 0xFFFFF000u) | jj;
    }
}

template <int SEGV>
__global__ __launch_bounds__(256) void chamfer_finish(
    const float* __restrict__ xyz1, const float* __restrict__ xyz2,
    const unsigned int* __restrict__ part, float* __restrict__ out)
{
    int gid = blockIdx.x * 256 + threadIdx.x;    // 0 .. 2*NB*NP-1
    int q   = gid & (NP - 1);
    int db  = gid >> 12;                          // dir*8+b
    int b   = db & 7;
    int dir = db >> 3;

    // Min-reduce packed partials across segments (lanes contiguous in q ->
    // each iteration is a coalesced 256B wave read, L2-resident).
    const unsigned int* base = part + ((size_t)db * SEGV) * NP + q;
    unsigned int p = 0xFFFFFFFFu;
    #pragma unroll
    for (int s = 0; s < SEGV; ++s) p = min(p, base[(size_t)s * NP]);

    const float* qset = dir ? xyz2 : xyz1;
    const float* tset = dir ? xyz1 : xyz2;

    float dist = __uint_as_float(p & 0xFFFFF000u);
    int j = (int)(p & 0xFFFu);

    const float* nq = qset + ((size_t)b * NP + q) * 6 + 3;
    const float* nt = tset + ((size_t)b * NP + j) * 6 + 3;
    float ax = nq[0], ay = nq[1], az = nq[2];
    float bx = nt[0], by = nt[1], bz = nt[2];

    float na = fmaxf(sqrtf(ax * ax + ay * ay + az * az), 1e-12f);
    float nb = fmaxf(sqrtf(bx * bx + by * by + bz * bz), 1e-12f);
    float ra = 1.0f / na, rb = 1.0f / nb;
    float dx = ax * ra - bx * rb;
    float dy = ay * ra - by * rb;
    float dz = az * ra - bz * rb;
    float nd = dx * dx + dy * dy + dz * dz;

    // mean over 8*4096 for each of {dist, nd} per direction; sum of 4 means.
    float contrib = (dist + nd) * (1.0f / 32768.0f);

    for (int off = 32; off > 0; off >>= 1)
        contrib += __shfl_down(contrib, off, 64);
    __shared__ float wsum[4];
    if ((threadIdx.x & 63) == 0) wsum[threadIdx.x >> 6] = contrib;
    __syncthreads();
    if (threadIdx.x == 0)
        atomicAdd(out, wsum[0] + wsum[1] + wsum[2] + wsum[3]);
}

extern "C" void kernel_launch(void* const* d_in, const int* in_sizes, int n_in,
                              void* d_out, int out_size, void* d_ws, size_t ws_size,
                              hipStream_t stream) {
    const float* xyz1 = (const float*)d_in[0];
    const float* xyz2 = (const float*)d_in[1];
    float* out = (float*)d_out;
    unsigned int* part = (unsigned int*)d_ws;

    size_t need32 = (size_t)2 * NB * 32 * NP * sizeof(unsigned int);  // 8 MB
    if (ws_size >= need32) {
        chamfer_argmin<32><<<2 * NB * NCHUNK * 32, THREADS, 0, stream>>>(xyz1, xyz2, part, out);
        chamfer_finish<32><<<(2 * NB * NP) / 256, 256, 0, stream>>>(xyz1, xyz2, part, out);
    } else {
        chamfer_argmin<16><<<2 * NB * NCHUNK * 16, THREADS, 0, stream>>>(xyz1, xyz2, part, out);
        chamfer_finish<16><<<(2 * NB * NP) / 256, 256, 0, stream>>>(xyz1, xyz2, part, out);
    }
}